// Round 5
// baseline (555.159 us; speedup 1.0000x reference)
//
#include <hip/hip_runtime.h>
#include <math.h>

#define NROWS 100000
#define NFEAT 50
#define NBINS 16
#define CELLS 5000000u   // NROWS * NFEAT
#define K1_BLOCKS 2500   // must be multiple of 25 so (blocks*256) % 50 == 0

// ---------------- Pass 1: reductions + mask compression ----------------
// Grid-stride over cells (one cell = 16 floats = one (n,f)). Thread count
// T % 50 == 0 so each thread's feature f is constant -> register accums.
// Per-block LDS reduce, then EXACT float atomicAdd to global finals
// (all sums are integer-valued, < 2^24 -> order-independent, exact).
template<bool WRITE_MASK>
__global__ __launch_bounds__(256) void k1(const float* __restrict__ x,
                                          const int* __restrict__ y,
                                          float* __restrict__ finals,
                                          int* __restrict__ n1,
                                          unsigned short* __restrict__ masks) {
  const unsigned tid  = threadIdx.x;
  const unsigned gtid = blockIdx.x * 256u + tid;
  const unsigned T    = gridDim.x * 256u;
  const int f = (int)(gtid % 50u);           // constant across the loop
  float s[16], s1[16];
#pragma unroll
  for (int i = 0; i < 16; ++i) { s[i] = 0.f; s1[i] = 0.f; }
  int ycnt = 0;
  for (unsigned c = gtid; c < CELLS; c += T) {
    const float4* xc = (const float4*)(x + (size_t)c * 16u);
    float4 v0 = xc[0], v1 = xc[1], v2 = xc[2], v3 = xc[3];
    const float fy = (float)y[c / 50u];      // y hot in L2 (400 KB)
    float vv[16] = {v0.x, v0.y, v0.z, v0.w, v1.x, v1.y, v1.z, v1.w,
                    v2.x, v2.y, v2.z, v2.w, v3.x, v3.y, v3.z, v3.w};
    unsigned m = 0u;
#pragma unroll
    for (int b = 0; b < 16; ++b) {
      float v = vv[b];
      s[b]  += v;
      s1[b] = fmaf(v, fy, s1[b]);            // v * y + s1 (exact: ints)
      m |= (v == 1.0f ? 1u : 0u) << b;
    }
    if (WRITE_MASK) masks[c] = (unsigned short)m;
    if (f == 0) ycnt += (fy != 0.0f);        // each row owned by its f==0 cell
  }
  __shared__ float lds[1600];
  __shared__ int ldsy;
  for (unsigned i = tid; i < 1600u; i += 256u) lds[i] = 0.f;
  if (tid == 0) ldsy = 0;
  __syncthreads();
#pragma unroll
  for (int b = 0; b < 16; ++b) {
    atomicAdd(&lds[f * 16 + b], s[b]);          // total sum
    atomicAdd(&lds[800 + f * 16 + b], s1[b]);   // sum over y==1
  }
  if (ycnt) atomicAdd(&ldsy, ycnt);
  __syncthreads();
  for (unsigned i = tid; i < 1600u; i += 256u) {
    float v = lds[i];
    if (v != 0.f) atomicAdd(&finals[i], v);     // exact integer-float adds
  }
  if (tid == 0 && ldsy) atomicAdd(n1, ldsy);
}

// ---- per-feature WLS/woe computation (device helper, deterministic) ----
// Computes woe[16] and adj[16] (adj[0] = woe[0]) for feature f from finals.
__device__ void wls_feature(const float* __restrict__ finals, int n1i, int f,
                            double* woe, double* adj) {
  const double n1 = (double)n1i;
  const double n0 = (double)NROWS - n1;
  double tp[16];
  for (int b = 0; b < 16; ++b) {
    double S  = (double)finals[f * 16 + b];
    double S1 = (double)finals[800 + f * 16 + b];
    double S0 = S - S1;
    woe[b] = log(S1 / n1 + 1e-4) - log(S0 / n0 + 1e-4);
    tp[b]  = S / (double)NROWS;
  }
  double w[15], p[15];
  double ps = 0.0;
  for (int k = 0; k < 15; ++k) { w[k] = woe[k + 1]; p[k] = tp[k + 1]; ps += p[k]; }
  for (int k = 0; k < 15; ++k) p[k] /= ps;
  int first = 0; bool found = false;
  for (int k = 0; k < 15; ++k) if (!found && p[k] != 0.0) { first = k; found = true; }
  double idx[15], ind[15];
  for (int k = 0; k < 15; ++k) {
    double t = (double)(k + 1 - first);
    idx[k] = t > 0.0 ? t : 0.0;
    ind[k] = (idx[k] != 0.0) ? 1.0 : 0.0;
  }
  double a00=0,a01=0,a02=0,a11=0,a12=0,a22=0,r0=0,r1v=0,r2v=0;
  for (int k = 0; k < 15; ++k) {
    double pi = p[k], id = idx[k], nd = ind[k], id2 = id * id;
    a00 += pi*nd*nd;  a01 += pi*nd*id;  a02 += pi*nd*id2;
    a11 += pi*id*id;  a12 += pi*id*id2; a22 += pi*id2*id2;
    r0  += pi*nd*w[k]; r1v += pi*id*w[k]; r2v += pi*id2*w[k];
  }
  double det2 = a00*a11 - a01*a01;
  double c10 = (a11*r0  - a01*r1v) / det2;
  double c11 = (a00*r1v - a01*r0 ) / det2;
  double m00 = a11*a22 - a12*a12;
  double m01 = a02*a12 - a01*a22;
  double m02 = a01*a12 - a02*a11;
  double det3 = a00*m00 + a01*m01 + a02*m02;
  double m11 = a00*a22 - a02*a02;
  double m12 = a01*a02 - a00*a12;
  double m22 = a00*a11 - a01*a01;
  double c20 = (m00*r0 + m01*r1v + m02*r2v) / det3;
  double c21 = (m01*r0 + m11*r1v + m12*r2v) / det3;
  double c22 = (m02*r0 + m12*r1v + m22*r2v) / det3;
  double mean = 0.0;
  for (int k = 0; k < 15; ++k) mean += w[k] * p[k];
  double sst = 0, sse1 = 0, sse2 = 0;
  double fit1[15], fit2[15];
  for (int k = 0; k < 15; ++k) {
    fit1[k] = ind[k]*c10 + idx[k]*c11;
    fit2[k] = ind[k]*c20 + idx[k]*c21 + idx[k]*idx[k]*c22;
    double d  = w[k] - mean;    sst  += d*d*p[k];
    double d1 = fit1[k] - w[k]; sse1 += d1*d1*p[k];
    double d2 = fit2[k] - w[k]; sse2 += d2*d2*p[k];
  }
  double R1 = 1.0 - sse1 / sst;
  double R2 = 1.0 - sse2 / sst;
  adj[0] = woe[0];
  for (int k = 0; k < 15; ++k)
    adj[k + 1] = (fit1[k]*R1 + fit2[k]*R2) / (R1 + R2);
}

// ---------------- Pass 3: WLS (per-block recompute) + rt ---------------
// Every block recomputes the tiny WLS step from finals into LDS (identical,
// deterministic across blocks); block 0 writes woe/adj outputs. Then the
// block streams rt from the bit-masks with its feature's weights in regs.
template<bool USE_MASK>
__global__ __launch_bounds__(256) void k3(const unsigned short* __restrict__ masks,
                                          const float* __restrict__ x,
                                          const float* __restrict__ finals,
                                          const int* __restrict__ n1p,
                                          float* __restrict__ out_woe,
                                          float* __restrict__ out_adj,
                                          float* __restrict__ rt) {
  __shared__ float sw[800];                  // w_use in LDS
  const unsigned tid = threadIdx.x;
  if (tid < NFEAT) {
    double woe[16], adj[16];
    wls_feature(finals, *n1p, (int)tid, woe, adj);
    for (int b = 0; b < 16; ++b) {
      float v = (float)adj[b];
      sw[tid * 16 + b] = isnan(v) ? 0.f : v;
      if (blockIdx.x == 0) {
        out_woe[tid * 16 + b] = (float)woe[b];
        out_adj[tid * 16 + b] = v;
      }
    }
  }
  __syncthreads();
  const unsigned gtid = blockIdx.x * 256u + tid;
  const unsigned T    = gridDim.x * 256u;
  const int f = (int)(gtid % 50u);
  float wr[16];
#pragma unroll
  for (int b = 0; b < 16; ++b) wr[b] = sw[f * 16 + b];
  for (unsigned c = gtid; c < CELLS; c += T) {
    float acc = 0.f;
    if (USE_MASK) {
      unsigned m = masks[c];
#pragma unroll
      for (int b = 0; b < 16; ++b) acc += ((m >> b) & 1u) ? wr[b] : 0.f;
    } else {
      const float4* xc = (const float4*)(x + (size_t)c * 16u);
      float4 v0 = xc[0], v1 = xc[1], v2 = xc[2], v3 = xc[3];
      float vv[16] = {v0.x, v0.y, v0.z, v0.w, v1.x, v1.y, v1.z, v1.w,
                      v2.x, v2.y, v2.z, v2.w, v3.x, v3.y, v3.z, v3.w};
#pragma unroll
      for (int b = 0; b < 16; ++b) acc += (vv[b] == 1.0f) ? wr[b] : 0.f;
    }
    rt[c] = acc;
  }
}

extern "C" void kernel_launch(void* const* d_in, const int* in_sizes, int n_in,
                              void* d_out, int out_size, void* d_ws, size_t ws_size,
                              hipStream_t stream) {
  const float* x = (const float*)d_in[0];
  const int*   y = (const int*)d_in[1];
  float* out     = (float*)d_out;
  float* rt      = out;                    // 5,000,000
  float* out_woe = out + 5000000;          // 800
  float* out_adj = out + 5000800;          // 800

  char* ws = (char*)d_ws;
  float* finals = (float*)ws;                         // 1600 floats
  int*   n1     = (int*)(finals + 1600);              // 1 int, contiguous
  unsigned short* masks = (unsigned short*)(ws + 8192);

  const bool use_mask = ws_size >= 8192 + (size_t)CELLS * 2;

  // zero the 6.4 KB accumulator region (graph-capturable async memset)
  hipMemsetAsync(finals, 0, 1600 * sizeof(float) + sizeof(int), stream);

  if (use_mask) {
    k1<true><<<K1_BLOCKS, 256, 0, stream>>>(x, y, finals, n1, masks);
    k3<true><<<2500, 256, 0, stream>>>(masks, nullptr, finals, n1,
                                       out_woe, out_adj, rt);
  } else {
    k1<false><<<K1_BLOCKS, 256, 0, stream>>>(x, y, finals, n1, nullptr);
    k3<false><<<2500, 256, 0, stream>>>(nullptr, x, finals, n1,
                                        out_woe, out_adj, rt);
  }
}

// Round 6
// 498.803 us; speedup vs baseline: 1.1130x; 1.1130x over previous
//
#include <hip/hip_runtime.h>
#include <math.h>

#define NROWS 100000
#define NFEAT 50
#define NBINS 16
#define CELLS 5000000u   // NROWS * NFEAT
#define K1_BLOCKS 2500   // must be multiple of 25 so (blocks*256) % 50 == 0

// ---------------- Pass 1: reductions + mask compression ----------------
// Grid-stride over cells (one cell = 16 floats = one (n,f)). Thread count
// T % 50 == 0 so each thread's feature f is constant -> register accums.
// Unroll x2: both cells' loads issue before any math (2x memory-level
// parallelism per wave; k1 was marginally latency-covered at 4 loads).
// Per-block LDS reduce, then EXACT float atomicAdd to global finals
// (all sums are integer-valued, < 2^24 -> order-independent, exact).
template<bool WRITE_MASK>
__global__ __launch_bounds__(256) void k1(const float* __restrict__ x,
                                          const int* __restrict__ y,
                                          float* __restrict__ finals,
                                          int* __restrict__ n1,
                                          unsigned short* __restrict__ masks) {
  const unsigned tid  = threadIdx.x;
  const unsigned gtid = blockIdx.x * 256u + tid;
  const unsigned T    = gridDim.x * 256u;
  const int f = (int)(gtid % 50u);           // constant across the loop
  float s[16], s1[16];
#pragma unroll
  for (int i = 0; i < 16; ++i) { s[i] = 0.f; s1[i] = 0.f; }
  int ycnt = 0;
  unsigned c = gtid;
  for (; c + T < CELLS; c += 2u * T) {
    const unsigned c2 = c + T;
    const float4* xa = (const float4*)(x + (size_t)c  * 16u);
    const float4* xb = (const float4*)(x + (size_t)c2 * 16u);
    float4 a0 = xa[0], a1 = xa[1], a2 = xa[2], a3 = xa[3];
    float4 b0 = xb[0], b1 = xb[1], b2 = xb[2], b3 = xb[3];
    const float fya = (float)y[c  / 50u];
    const float fyb = (float)y[c2 / 50u];
    float va[16] = {a0.x, a0.y, a0.z, a0.w, a1.x, a1.y, a1.z, a1.w,
                    a2.x, a2.y, a2.z, a2.w, a3.x, a3.y, a3.z, a3.w};
    float vb[16] = {b0.x, b0.y, b0.z, b0.w, b1.x, b1.y, b1.z, b1.w,
                    b2.x, b2.y, b2.z, b2.w, b3.x, b3.y, b3.z, b3.w};
    unsigned ma = 0u, mb = 0u;
#pragma unroll
    for (int b = 0; b < 16; ++b) {
      float u = va[b], v = vb[b];
      s[b]  += u + v;
      s1[b] = fmaf(u, fya, s1[b]);
      s1[b] = fmaf(v, fyb, s1[b]);
      ma |= (u == 1.0f ? 1u : 0u) << b;
      mb |= (v == 1.0f ? 1u : 0u) << b;
    }
    if (WRITE_MASK) { masks[c] = (unsigned short)ma; masks[c2] = (unsigned short)mb; }
    if (f == 0) ycnt += (fya != 0.0f) + (fyb != 0.0f);
  }
  if (c < CELLS) {
    const float4* xa = (const float4*)(x + (size_t)c * 16u);
    float4 a0 = xa[0], a1 = xa[1], a2 = xa[2], a3 = xa[3];
    const float fya = (float)y[c / 50u];
    float va[16] = {a0.x, a0.y, a0.z, a0.w, a1.x, a1.y, a1.z, a1.w,
                    a2.x, a2.y, a2.z, a2.w, a3.x, a3.y, a3.z, a3.w};
    unsigned ma = 0u;
#pragma unroll
    for (int b = 0; b < 16; ++b) {
      float u = va[b];
      s[b]  += u;
      s1[b] = fmaf(u, fya, s1[b]);
      ma |= (u == 1.0f ? 1u : 0u) << b;
    }
    if (WRITE_MASK) masks[c] = (unsigned short)ma;
    if (f == 0) ycnt += (fya != 0.0f);
  }
  __shared__ float lds[1600];
  __shared__ int ldsy;
  for (unsigned i = tid; i < 1600u; i += 256u) lds[i] = 0.f;
  if (tid == 0) ldsy = 0;
  __syncthreads();
#pragma unroll
  for (int b = 0; b < 16; ++b) {
    atomicAdd(&lds[f * 16 + b], s[b]);          // total sum
    atomicAdd(&lds[800 + f * 16 + b], s1[b]);   // sum over y==1
  }
  if (ycnt) atomicAdd(&ldsy, ycnt);
  __syncthreads();
  for (unsigned i = tid; i < 1600u; i += 256u) {
    float v = lds[i];
    if (v != 0.f) atomicAdd(&finals[i], v);     // exact integer-float adds
  }
  if (tid == 0 && ldsy) atomicAdd(n1, ldsy);
}

// ---------------- Pass 2: woe + WLS fits (tiny, 1 block) ---------------
__global__ __launch_bounds__(64) void k2(const float* __restrict__ finals,
                                         const int* __restrict__ n1p,
                                         float* __restrict__ out_woe,
                                         float* __restrict__ out_adj,
                                         float* __restrict__ w_use) {
  const int tid = threadIdx.x;
  if (tid >= NFEAT) return;
  const int f = tid;
  const double n1 = (double)(*n1p);
  const double n0 = (double)NROWS - n1;
  double woe[16], tp[16];
  for (int b = 0; b < 16; ++b) {
    double S  = (double)finals[f * 16 + b];
    double S1 = (double)finals[800 + f * 16 + b];
    double S0 = S - S1;
    woe[b] = log(S1 / n1 + 1e-4) - log(S0 / n0 + 1e-4);
    tp[b]  = S / (double)NROWS;
    out_woe[f * 16 + b] = (float)woe[b];
  }
  double w[15], p[15];
  double ps = 0.0;
  for (int k = 0; k < 15; ++k) { w[k] = woe[k + 1]; p[k] = tp[k + 1]; ps += p[k]; }
  for (int k = 0; k < 15; ++k) p[k] /= ps;
  int first = 0; bool found = false;
  for (int k = 0; k < 15; ++k) if (!found && p[k] != 0.0) { first = k; found = true; }
  double idx[15], ind[15];
  for (int k = 0; k < 15; ++k) {
    double t = (double)(k + 1 - first);
    idx[k] = t > 0.0 ? t : 0.0;
    ind[k] = (idx[k] != 0.0) ? 1.0 : 0.0;
  }
  double a00=0,a01=0,a02=0,a11=0,a12=0,a22=0,r0=0,r1v=0,r2v=0;
  for (int k = 0; k < 15; ++k) {
    double pi = p[k], id = idx[k], nd = ind[k], id2 = id * id;
    a00 += pi*nd*nd;  a01 += pi*nd*id;  a02 += pi*nd*id2;
    a11 += pi*id*id;  a12 += pi*id*id2; a22 += pi*id2*id2;
    r0  += pi*nd*w[k]; r1v += pi*id*w[k]; r2v += pi*id2*w[k];
  }
  double det2 = a00*a11 - a01*a01;
  double c10 = (a11*r0  - a01*r1v) / det2;
  double c11 = (a00*r1v - a01*r0 ) / det2;
  double m00 = a11*a22 - a12*a12;
  double m01 = a02*a12 - a01*a22;
  double m02 = a01*a12 - a02*a11;
  double det3 = a00*m00 + a01*m01 + a02*m02;
  double m11 = a00*a22 - a02*a02;
  double m12 = a01*a02 - a00*a12;
  double m22 = a00*a11 - a01*a01;
  double c20 = (m00*r0 + m01*r1v + m02*r2v) / det3;
  double c21 = (m01*r0 + m11*r1v + m12*r2v) / det3;
  double c22 = (m02*r0 + m12*r1v + m22*r2v) / det3;
  double mean = 0.0;
  for (int k = 0; k < 15; ++k) mean += w[k] * p[k];
  double sst = 0, sse1 = 0, sse2 = 0;
  double fit1[15], fit2[15];
  for (int k = 0; k < 15; ++k) {
    fit1[k] = ind[k]*c10 + idx[k]*c11;
    fit2[k] = ind[k]*c20 + idx[k]*c21 + idx[k]*idx[k]*c22;
    double d  = w[k] - mean;    sst  += d*d*p[k];
    double d1 = fit1[k] - w[k]; sse1 += d1*d1*p[k];
    double d2 = fit2[k] - w[k]; sse2 += d2*d2*p[k];
  }
  double R1 = 1.0 - sse1 / sst;
  double R2 = 1.0 - sse2 / sst;
  {
    float v = (float)woe[0];
    out_adj[f * 16] = v;
    w_use[f * 16] = isnan(v) ? 0.f : v;
  }
  for (int k = 0; k < 15; ++k) {
    double adj = (fit1[k]*R1 + fit2[k]*R2) / (R1 + R2);
    float v = (float)adj;
    out_adj[f * 16 + 1 + k] = v;
    w_use[f * 16 + 1 + k] = isnan(v) ? 0.f : v;
  }
}

// ---------------- Pass 3: rt from masks (or x fallback) ----------------
template<bool USE_MASK>
__global__ __launch_bounds__(256) void k3(const unsigned short* __restrict__ masks,
                                          const float* __restrict__ x,
                                          const float* __restrict__ w_use,
                                          float* __restrict__ rt) {
  const unsigned gtid = blockIdx.x * 256u + threadIdx.x;
  const unsigned T    = gridDim.x * 256u;
  const int f = (int)(gtid % 50u);
  const float4* wf = (const float4*)(w_use + f * 16);
  float4 w0 = wf[0], w1 = wf[1], w2 = wf[2], w3 = wf[3];
  float wr[16] = {w0.x, w0.y, w0.z, w0.w, w1.x, w1.y, w1.z, w1.w,
                  w2.x, w2.y, w2.z, w2.w, w3.x, w3.y, w3.z, w3.w};
  for (unsigned c = gtid; c < CELLS; c += T) {
    float acc = 0.f;
    if (USE_MASK) {
      unsigned m = masks[c];
#pragma unroll
      for (int b = 0; b < 16; ++b) acc += ((m >> b) & 1u) ? wr[b] : 0.f;
    } else {
      const float4* xc = (const float4*)(x + (size_t)c * 16u);
      float4 v0 = xc[0], v1 = xc[1], v2 = xc[2], v3 = xc[3];
      float vv[16] = {v0.x, v0.y, v0.z, v0.w, v1.x, v1.y, v1.z, v1.w,
                      v2.x, v2.y, v2.z, v2.w, v3.x, v3.y, v3.z, v3.w};
#pragma unroll
      for (int b = 0; b < 16; ++b) acc += (vv[b] == 1.0f) ? wr[b] : 0.f;
    }
    rt[c] = acc;
  }
}

extern "C" void kernel_launch(void* const* d_in, const int* in_sizes, int n_in,
                              void* d_out, int out_size, void* d_ws, size_t ws_size,
                              hipStream_t stream) {
  const float* x = (const float*)d_in[0];
  const int*   y = (const int*)d_in[1];
  float* out     = (float*)d_out;
  float* rt      = out;                    // 5,000,000
  float* out_woe = out + 5000000;          // 800
  float* out_adj = out + 5000800;          // 800

  char* ws = (char*)d_ws;
  float* finals = (float*)ws;                         // 1600 floats
  int*   n1     = (int*)(finals + 1600);              // 1 int, contiguous
  float* w_use  = (float*)(n1 + 64);                  // 800 floats
  unsigned short* masks = (unsigned short*)(ws + 16384);

  const bool use_mask = ws_size >= 16384 + (size_t)CELLS * 2;

  // zero the accumulator region (graph-capturable async memset)
  hipMemsetAsync(finals, 0, 1600 * sizeof(float) + sizeof(int), stream);

  if (use_mask) {
    k1<true><<<K1_BLOCKS, 256, 0, stream>>>(x, y, finals, n1, masks);
    k2<<<1, 64, 0, stream>>>(finals, n1, out_woe, out_adj, w_use);
    k3<true><<<2500, 256, 0, stream>>>(masks, nullptr, w_use, rt);
  } else {
    k1<false><<<K1_BLOCKS, 256, 0, stream>>>(x, y, finals, n1, nullptr);
    k2<<<1, 64, 0, stream>>>(finals, n1, out_woe, out_adj, w_use);
    k3<false><<<2500, 256, 0, stream>>>(nullptr, x, w_use, rt);
  }
}